// Round 5
// baseline (446.563 us; speedup 1.0000x reference)
//
#include <hip/hip_runtime.h>

constexpr int RESI   = 128;
constexpr int NSTEPS = 512;
// Tiled bitfield: 8x8x8 voxel block = 512 bits = 64 B = one cache line.
// Per batch: 16x16x16 blocks * 16 u32 = 65536 u32 (256 KB). 4 batches = 1 MB.
constexpr int GRID_WORDS_PER_BATCH = 65536;

typedef float v4f __attribute__((ext_vector_type(4)));  // native vec for nt-store

// Pack int32 0/1 occupancy -> tiled bitfield. One thread per output u32 word.
// Word w (within batch): blockid = w>>4 = (bx*16+by)*16+bz ; wib = w&15.
//   gx = bx*8 + (wib>>1); gy base = by*8 + (wib&1)*4 (4 rows); gz = bz*8..+8.
//   bit j = a*8 + c  with gy = gybase+a, gz = gzbase+c.
__global__ __launch_bounds__(256) void occ_pack_tiled_kernel(
    const int* __restrict__ occ, unsigned int* __restrict__ bits)
{
    const int w = blockIdx.x * blockDim.x + threadIdx.x;   // global word id
    const int b   = w >> 16;
    const int rem = w & 65535;
    const int blockid = rem >> 4;
    const int wib     = rem & 15;
    const int bx = blockid >> 8;
    const int by = (blockid >> 4) & 15;
    const int bz = blockid & 15;
    const int gx  = bx * 8 + (wib >> 1);
    const int gy0 = by * 8 + (wib & 1) * 4;
    const int gz0 = bz * 8;

    const int* __restrict__ src = occ + (((size_t)b * RESI + gx) * RESI + gy0) * RESI + gz0;

    unsigned int word = 0;
#pragma unroll
    for (int a = 0; a < 4; ++a) {
        const int* row = src + a * RESI;
#pragma unroll
        for (int c = 0; c < 8; ++c) {
            const int v = __builtin_nontemporal_load(row + c);  // one-shot read, don't pollute L2
            word |= (v != 0 ? 1u : 0u) << (a * 8 + c);
        }
    }
    bits[w] = word;
}

__global__ __launch_bounds__(128) void occ_march_kernel(
    const unsigned int* __restrict__ gridbits,  // tiled, [4, 65536]
    const float* __restrict__ rays_o,           // [N,3]
    const float* __restrict__ rays_d,           // [N,3]
    const int*   __restrict__ rays_bidx,        // [N]
    float*       __restrict__ out_pts,          // [N,512,3]
    float*       __restrict__ out_t,            // [N,512]
    float*       __restrict__ out_mask,         // [N,512] as 0.0/1.0
    int n_rays)
{
#pragma clang fp contract(off)
    const int ray = blockIdx.x;
    if (ray >= n_rays) return;

    const float ox = rays_o[3 * ray + 0];
    const float oy = rays_o[3 * ray + 1];
    const float oz = rays_o[3 * ray + 2];
    const float dx = rays_d[3 * ray + 0];
    const float dy = rays_d[3 * ray + 1];
    const float dz = rays_d[3 * ray + 2];
    const int   b  = rays_bidx[ray];

    // safe_d / inv_d exactly as the reference (fp32 IEEE div, no fast-math)
    const float eps = 1e-10f;
    const float sdx = (fabsf(dx) < eps) ? ((dx >= 0.0f) ? eps : -eps) : dx;
    const float sdy = (fabsf(dy) < eps) ? ((dy >= 0.0f) ? eps : -eps) : dy;
    const float sdz = (fabsf(dz) < eps) ? ((dz >= 0.0f) ? eps : -eps) : dz;
    const float invx = 1.0f / sdx;
    const float invy = 1.0f / sdy;
    const float invz = 1.0f / sdz;

    const float t0x = (-1.0f - ox) * invx;
    const float t1x = ( 1.0f - ox) * invx;
    const float t0y = (-1.0f - oy) * invy;
    const float t1y = ( 1.0f - oy) * invy;
    const float t0z = (-1.0f - oz) * invz;
    const float t1z = ( 1.0f - oz) * invz;

    const float tmin = fmaxf(fmaxf(fminf(t0x, t1x), fminf(t0y, t1y)), fminf(t0z, t1z));
    const float tmax = fminf(fminf(fmaxf(t0x, t1x), fmaxf(t0y, t1y)), fmaxf(t0z, t1z));
    const float nearv  = fmaxf(tmin, 0.0f);
    const bool  ray_ok = (tmax > nearv);

    const unsigned int* __restrict__ gb = gridbits + (size_t)b * GRID_WORDS_PER_BATCH;

    const int s0 = (int)threadIdx.x * 4;   // 128 threads x 4 steps = 512

    float tv[4], mv[4], p[12];

#pragma unroll
    for (int i = 0; i < 4; ++i) {
        const int   s  = s0 + i;
        // t = near + (s + 0.5)*STEP  -- mul then add, NOT fused (pragma above)
        const float ts = nearv + ((float)s + 0.5f) * 0.005f;
        // pts = o + t*d  -- mul then add, NOT fused
        const float px = ox + ts * dx;
        const float py = oy + ts * dy;
        const float pz = oz + ts * dz;

        const bool in_box = ray_ok && (ts < tmax);

        bool m = false;
        if (in_box) {   // exec-mask predication: out-of-box lanes skip the gather
            // gidx = clip(int((p*0.5+0.5)*128), 0, 127); trunc toward 0 = astype
            int gx = (int)((px * 0.5f + 0.5f) * 128.0f);
            int gy = (int)((py * 0.5f + 0.5f) * 128.0f);
            int gz = (int)((pz * 0.5f + 0.5f) * 128.0f);
            gx = min(max(gx, 0), RESI - 1);
            gy = min(max(gy, 0), RESI - 1);
            gz = min(max(gz, 0), RESI - 1);

            // tiled address: block (gx>>3,gy>>3,gz>>3) -> 16 words; see pack kernel
            const unsigned int blockid = ((unsigned)(gx >> 3) << 8) |
                                         ((unsigned)(gy >> 3) << 4) |
                                          (unsigned)(gz >> 3);
            const unsigned int wib    = (((unsigned)gx & 7u) << 1) | (((unsigned)gy >> 2) & 1u);
            const unsigned int word   = gb[(blockid << 4) | wib];
            const unsigned int bitpos = (((unsigned)gy & 3u) << 3) | ((unsigned)gz & 7u);
            m = (word >> bitpos) & 1u;
        }

        tv[i] = ts;
        mv[i] = m ? 1.0f : 0.0f;
        p[3 * i + 0] = m ? px : 0.0f;
        p[3 * i + 1] = m ? py : 0.0f;
        p[3 * i + 2] = m ? pz : 0.0f;
    }

    const size_t base = (size_t)ray * NSTEPS + (size_t)s0;

    // Write-only output streams: nontemporal so 335 MB of stores don't evict
    // the 1 MB grid from L2 (gathers stay L2-resident).
    const v4f vt = { tv[0], tv[1], tv[2], tv[3] };
    const v4f vm = { mv[0], mv[1], mv[2], mv[3] };
    __builtin_nontemporal_store(vt, (v4f*)(out_t    + base));
    __builtin_nontemporal_store(vm, (v4f*)(out_mask + base));

    v4f* pp = (v4f*)(out_pts + base * 3);   // 48B per lane, 3 x float4
    const v4f vp0 = { p[0], p[1], p[2],  p[3]  };
    const v4f vp1 = { p[4], p[5], p[6],  p[7]  };
    const v4f vp2 = { p[8], p[9], p[10], p[11] };
    __builtin_nontemporal_store(vp0, pp + 0);
    __builtin_nontemporal_store(vp1, pp + 1);
    __builtin_nontemporal_store(vp2, pp + 2);
}

extern "C" void kernel_launch(void* const* d_in, const int* in_sizes, int n_in,
                              void* d_out, int out_size, void* d_ws, size_t ws_size,
                              hipStream_t stream) {
    const int*   occ    = (const int*)  d_in[0];  // bool -> int32
    const float* rays_o = (const float*)d_in[1];
    const float* rays_d = (const float*)d_in[2];
    const int*   bidx   = (const int*)  d_in[3];

    const int n_rays = in_sizes[3];
    const int n_vox  = in_sizes[0];               // 4*128^3 = 8388608
    const int n_words = n_vox / 32;               // 262144

    float* out      = (float*)d_out;
    float* out_pts  = out;                                    // [N,512,3]
    float* out_t    = out + (size_t)n_rays * NSTEPS * 3;      // [N,512]
    float* out_mask = out_t + (size_t)n_rays * NSTEPS;        // [N,512]

    unsigned int* bits = (unsigned int*)d_ws;                 // 1 MB tiled grid

    occ_pack_tiled_kernel<<<n_words / 256, 256, 0, stream>>>(occ, bits);
    occ_march_kernel<<<n_rays, 128, 0, stream>>>(bits, rays_o, rays_d, bidx,
                                                 out_pts, out_t, out_mask, n_rays);
}

// Round 6
// 375.949 us; speedup vs baseline: 1.1878x; 1.1878x over previous
//
#include <hip/hip_runtime.h>

constexpr int RESI   = 128;
constexpr int NSTEPS = 512;
// Tiled bitfield: 8x8x8 voxel block = 512 bits = 64 B = one cache line.
// Per batch: 16x16x16 blocks * 16 u32 = 65536 u32 (256 KB). 4 batches = 1 MB.
constexpr int GRID_WORDS_PER_BATCH = 65536;

// Pack int32 0/1 occupancy -> tiled bitfield. One thread per output u32 word.
// Word w (within batch): blockid = w>>4 = (bx*16+by)*16+bz ; wib = w&15.
//   gx = bx*8 + (wib>>1); gy base = by*8 + (wib&1)*4 (4 rows); gz = bz*8..+8.
//   bit j = a*8 + c  with gy = gybase+a, gz = gzbase+c.
__global__ __launch_bounds__(256) void occ_pack_tiled_kernel(
    const int* __restrict__ occ, unsigned int* __restrict__ bits)
{
    const int w = blockIdx.x * blockDim.x + threadIdx.x;   // global word id
    const int b   = w >> 16;
    const int rem = w & 65535;
    const int blockid = rem >> 4;
    const int wib     = rem & 15;
    const int bx = blockid >> 8;
    const int by = (blockid >> 4) & 15;
    const int bz = blockid & 15;
    const int gx  = bx * 8 + (wib >> 1);
    const int gy0 = by * 8 + (wib & 1) * 4;
    const int gz0 = bz * 8;

    const int* __restrict__ src = occ + (((size_t)b * RESI + gx) * RESI + gy0) * RESI + gz0;

    unsigned int word = 0;
#pragma unroll
    for (int a = 0; a < 4; ++a) {
        const int* row = src + a * RESI;
#pragma unroll
        for (int c = 0; c < 8; ++c) {
            const int v = __builtin_nontemporal_load(row + c);  // one-shot read, keep L2 clean
            word |= (v != 0 ? 1u : 0u) << (a * 8 + c);
        }
    }
    bits[w] = word;
}

// Persistent march kernel: 256 threads = 2 rays per iteration (128 thr/ray),
// grid-stride over ray pairs. Branchless, MLP=4 gathers.
__global__ __launch_bounds__(256) void occ_march_kernel(
    const unsigned int* __restrict__ gridbits,  // tiled, [4, 65536]
    const float* __restrict__ rays_o,           // [N,3]
    const float* __restrict__ rays_d,           // [N,3]
    const int*   __restrict__ rays_bidx,        // [N]
    float*       __restrict__ out_pts,          // [N,512,3]
    float*       __restrict__ out_t,            // [N,512]
    float*       __restrict__ out_mask,         // [N,512] as 0.0/1.0
    int n_rays)
{
#pragma clang fp contract(off)
    const int n_pairs = n_rays >> 1;
    const int sub  = threadIdx.x >> 7;          // which of the 2 rays
    const int tid  = threadIdx.x & 127;         // thread within ray
    const int s0   = tid * 4;                   // 4 consecutive steps

    for (int pair = blockIdx.x; pair < n_pairs; pair += gridDim.x) {
        const int ray = pair * 2 + sub;

        const float ox = rays_o[3 * ray + 0];
        const float oy = rays_o[3 * ray + 1];
        const float oz = rays_o[3 * ray + 2];
        const float dx = rays_d[3 * ray + 0];
        const float dy = rays_d[3 * ray + 1];
        const float dz = rays_d[3 * ray + 2];
        const int   b  = rays_bidx[ray];

        // safe_d / inv_d exactly as the reference (fp32 IEEE div, no fast-math)
        const float eps = 1e-10f;
        const float sdx = (fabsf(dx) < eps) ? ((dx >= 0.0f) ? eps : -eps) : dx;
        const float sdy = (fabsf(dy) < eps) ? ((dy >= 0.0f) ? eps : -eps) : dy;
        const float sdz = (fabsf(dz) < eps) ? ((dz >= 0.0f) ? eps : -eps) : dz;
        const float invx = 1.0f / sdx;
        const float invy = 1.0f / sdy;
        const float invz = 1.0f / sdz;

        const float t0x = (-1.0f - ox) * invx;
        const float t1x = ( 1.0f - ox) * invx;
        const float t0y = (-1.0f - oy) * invy;
        const float t1y = ( 1.0f - oy) * invy;
        const float t0z = (-1.0f - oz) * invz;
        const float t1z = ( 1.0f - oz) * invz;

        const float tmin = fmaxf(fmaxf(fminf(t0x, t1x), fminf(t0y, t1y)), fminf(t0z, t1z));
        const float tmax = fminf(fminf(fmaxf(t0x, t1x), fmaxf(t0y, t1y)), fmaxf(t0z, t1z));
        const float nearv  = fmaxf(tmin, 0.0f);
        const bool  ray_ok = (tmax > nearv);

        const unsigned int* __restrict__ gb = gridbits + (size_t)b * GRID_WORDS_PER_BATCH;

        float tv[4], px[4], py[4], pz[4];
        unsigned int widx[4], bitpos[4];
        bool in_box[4];

        // Phase 1: all addresses (no loads yet)
#pragma unroll
        for (int i = 0; i < 4; ++i) {
            const int s = s0 + i;
            const float ts = nearv + ((float)s + 0.5f) * 0.005f;   // mul+add, not fused
            const float x = ox + ts * dx;                           // mul+add, not fused
            const float y = oy + ts * dy;
            const float z = oz + ts * dz;
            tv[i] = ts; px[i] = x; py[i] = y; pz[i] = z;
            in_box[i] = ray_ok && (ts < tmax);

            int gx = (int)((x * 0.5f + 0.5f) * 128.0f);
            int gy = (int)((y * 0.5f + 0.5f) * 128.0f);
            int gz = (int)((z * 0.5f + 0.5f) * 128.0f);
            gx = min(max(gx, 0), RESI - 1);
            gy = min(max(gy, 0), RESI - 1);
            gz = min(max(gz, 0), RESI - 1);

            const unsigned int blockid = ((unsigned)(gx >> 3) << 8) |
                                         ((unsigned)(gy >> 3) << 4) |
                                          (unsigned)(gz >> 3);
            const unsigned int wib = (((unsigned)gx & 7u) << 1) | (((unsigned)gy >> 2) & 1u);
            widx[i]   = (blockid << 4) | wib;
            bitpos[i] = (((unsigned)gy & 3u) << 3) | ((unsigned)gz & 7u);
        }

        // Phase 2: 4 independent gathers in flight (MLP=4, branchless)
        unsigned int wrd[4];
#pragma unroll
        for (int i = 0; i < 4; ++i) wrd[i] = gb[widx[i]];

        // Phase 3: masks + output
        float mv[4], p[12];
#pragma unroll
        for (int i = 0; i < 4; ++i) {
            const bool m = in_box[i] && ((wrd[i] >> bitpos[i]) & 1u);
            mv[i] = m ? 1.0f : 0.0f;
            p[3 * i + 0] = m ? px[i] : 0.0f;
            p[3 * i + 1] = m ? py[i] : 0.0f;
            p[3 * i + 2] = m ? pz[i] : 0.0f;
        }

        const size_t base = (size_t)ray * NSTEPS + (size_t)s0;

        *(float4*)(out_t    + base) = make_float4(tv[0], tv[1], tv[2], tv[3]);
        *(float4*)(out_mask + base) = make_float4(mv[0], mv[1], mv[2], mv[3]);

        float4* pp = (float4*)(out_pts + base * 3);   // 48B per lane, 3 x float4
        pp[0] = make_float4(p[0], p[1], p[2],  p[3]);
        pp[1] = make_float4(p[4], p[5], p[6],  p[7]);
        pp[2] = make_float4(p[8], p[9], p[10], p[11]);
    }
}

extern "C" void kernel_launch(void* const* d_in, const int* in_sizes, int n_in,
                              void* d_out, int out_size, void* d_ws, size_t ws_size,
                              hipStream_t stream) {
    const int*   occ    = (const int*)  d_in[0];  // bool -> int32
    const float* rays_o = (const float*)d_in[1];
    const float* rays_d = (const float*)d_in[2];
    const int*   bidx   = (const int*)  d_in[3];

    const int n_rays = in_sizes[3];
    const int n_vox  = in_sizes[0];               // 4*128^3 = 8388608
    const int n_words = n_vox / 32;               // 262144

    float* out      = (float*)d_out;
    float* out_pts  = out;                                    // [N,512,3]
    float* out_t    = out + (size_t)n_rays * NSTEPS * 3;      // [N,512]
    float* out_mask = out_t + (size_t)n_rays * NSTEPS;        // [N,512]

    unsigned int* bits = (unsigned int*)d_ws;                 // 1 MB tiled grid

    occ_pack_tiled_kernel<<<n_words / 256, 256, 0, stream>>>(occ, bits);
    // Persistent: 2048 blocks (8/CU), grid-stride over 16384 ray pairs.
    occ_march_kernel<<<2048, 256, 0, stream>>>(bits, rays_o, rays_d, bidx,
                                               out_pts, out_t, out_mask, n_rays);
}

// Round 7
// 366.894 us; speedup vs baseline: 1.2171x; 1.0247x over previous
//
#include <hip/hip_runtime.h>

constexpr int RESI   = 128;
constexpr int NSTEPS = 512;
// Tiled bitfield: 8x8x8 voxel block = 512 bits = 64 B = one cache line.
constexpr int GRID_WORDS_PER_BATCH = 65536;

typedef float v4f __attribute__((ext_vector_type(4)));

// Pack int32 0/1 occupancy -> tiled bitfield. One thread per output u32 word.
__global__ __launch_bounds__(256) void occ_pack_tiled_kernel(
    const int* __restrict__ occ, unsigned int* __restrict__ bits)
{
    const int w = blockIdx.x * blockDim.x + threadIdx.x;   // global word id
    const int b   = w >> 16;
    const int rem = w & 65535;
    const int blockid = rem >> 4;
    const int wib     = rem & 15;
    const int bx = blockid >> 8;
    const int by = (blockid >> 4) & 15;
    const int bz = blockid & 15;
    const int gx  = bx * 8 + (wib >> 1);
    const int gy0 = by * 8 + (wib & 1) * 4;
    const int gz0 = bz * 8;

    const int* __restrict__ src = occ + (((size_t)b * RESI + gx) * RESI + gy0) * RESI + gz0;

    unsigned int word = 0;
#pragma unroll
    for (int a = 0; a < 4; ++a) {
        const int* row = src + a * RESI;
#pragma unroll
        for (int c = 0; c < 8; ++c) {
            const int v = __builtin_nontemporal_load(row + c);  // one-shot read
            word |= (v != 0 ? 1u : 0u) << (a * 8 + c);
        }
    }
    bits[w] = word;
}

__global__ __launch_bounds__(128) void occ_march_kernel(
    const unsigned int* __restrict__ gridbits,  // tiled, [4, 65536]
    const float* __restrict__ rays_o,           // [N,3]
    const float* __restrict__ rays_d,           // [N,3]
    const int*   __restrict__ rays_bidx,        // [N]
    float*       __restrict__ out_pts,          // [N,512,3]
    float*       __restrict__ out_t,            // [N,512]
    float*       __restrict__ out_mask,         // [N,512] as 0.0/1.0
    int n_rays)
{
#pragma clang fp contract(off)
    // Per-wave pts staging: 192 slots x 16B = 3KB/wave, 2 waves = 6KB/block.
    __shared__ v4f sp[192 * 2];

    const int ray = blockIdx.x;
    if (ray >= n_rays) return;

    const int tid  = threadIdx.x;
    const int lane = tid & 63;
    const int wv   = tid >> 6;
    const int s0   = tid * 4;

    const float ox = rays_o[3 * ray + 0];
    const float oy = rays_o[3 * ray + 1];
    const float oz = rays_o[3 * ray + 2];
    const float dx = rays_d[3 * ray + 0];
    const float dy = rays_d[3 * ray + 1];
    const float dz = rays_d[3 * ray + 2];
    const int   b  = rays_bidx[ray];

    // safe_d / inv_d exactly as the reference (fp32 IEEE div, no fast-math)
    const float eps = 1e-10f;
    const float sdx = (fabsf(dx) < eps) ? ((dx >= 0.0f) ? eps : -eps) : dx;
    const float sdy = (fabsf(dy) < eps) ? ((dy >= 0.0f) ? eps : -eps) : dy;
    const float sdz = (fabsf(dz) < eps) ? ((dz >= 0.0f) ? eps : -eps) : dz;
    const float invx = 1.0f / sdx;
    const float invy = 1.0f / sdy;
    const float invz = 1.0f / sdz;

    const float t0x = (-1.0f - ox) * invx;
    const float t1x = ( 1.0f - ox) * invx;
    const float t0y = (-1.0f - oy) * invy;
    const float t1y = ( 1.0f - oy) * invy;
    const float t0z = (-1.0f - oz) * invz;
    const float t1z = ( 1.0f - oz) * invz;

    const float tmin = fmaxf(fmaxf(fminf(t0x, t1x), fminf(t0y, t1y)), fminf(t0z, t1z));
    const float tmax = fminf(fminf(fmaxf(t0x, t1x), fmaxf(t0y, t1y)), fmaxf(t0z, t1z));
    const float nearv  = fmaxf(tmin, 0.0f);
    const bool  ray_ok = (tmax > nearv);

    const unsigned int* __restrict__ gb = gridbits + (size_t)b * GRID_WORDS_PER_BATCH;

    float tv[4], px[4], py[4], pz[4];
    unsigned int widx[4], bitpos[4];
    bool in_box[4];

    // Phase 1: addresses + positions (no loads yet)
#pragma unroll
    for (int i = 0; i < 4; ++i) {
        const int s = s0 + i;
        const float ts = nearv + ((float)s + 0.5f) * 0.005f;   // mul+add, not fused
        const float x = ox + ts * dx;                           // mul+add, not fused
        const float y = oy + ts * dy;
        const float z = oz + ts * dz;
        tv[i] = ts; px[i] = x; py[i] = y; pz[i] = z;
        in_box[i] = ray_ok && (ts < tmax);

        int gx = (int)((x * 0.5f + 0.5f) * 128.0f);
        int gy = (int)((y * 0.5f + 0.5f) * 128.0f);
        int gz = (int)((z * 0.5f + 0.5f) * 128.0f);
        gx = min(max(gx, 0), RESI - 1);
        gy = min(max(gy, 0), RESI - 1);
        gz = min(max(gz, 0), RESI - 1);

        const unsigned int blockid = ((unsigned)(gx >> 3) << 8) |
                                     ((unsigned)(gy >> 3) << 4) |
                                      (unsigned)(gz >> 3);
        const unsigned int wib = (((unsigned)gx & 7u) << 1) | (((unsigned)gy >> 2) & 1u);
        widx[i]   = (blockid << 4) | wib;
        bitpos[i] = (((unsigned)gy & 3u) << 3) | ((unsigned)gz & 7u);
    }

    // Phase 2: 4 independent gathers in flight
    unsigned int wrd[4];
#pragma unroll
    for (int i = 0; i < 4; ++i) wrd[i] = gb[widx[i]];

    // Phase 3: masks
    float mv[4], p[12];
#pragma unroll
    for (int i = 0; i < 4; ++i) {
        const bool m = in_box[i] && ((wrd[i] >> bitpos[i]) & 1u);
        mv[i] = m ? 1.0f : 0.0f;
        p[3 * i + 0] = m ? px[i] : 0.0f;
        p[3 * i + 1] = m ? py[i] : 0.0f;
        p[3 * i + 2] = m ? pz[i] : 0.0f;
    }

    const size_t base = (size_t)ray * NSTEPS + (size_t)s0;

    // t / mask: already lane-contiguous float4 streams (1 req/line).
    const v4f vt = { tv[0], tv[1], tv[2], tv[3] };
    const v4f vm = { mv[0], mv[1], mv[2], mv[3] };
    *(v4f*)(out_t    + base) = vt;
    *(v4f*)(out_mask + base) = vm;

    // pts: transpose through LDS so global stores are lane-contiguous float4.
    // Wave region = 192 16B slots (3KB). Logical slot L; phys P = L ^ ((L>>3)&7)
    // keeps 16B alignment, makes the thread-major write phase conflict-free and
    // the lane-major read phase 2-way (free).
    v4f* wbuf = sp + 192 * wv;
#pragma unroll
    for (int k = 0; k < 3; ++k) {
        const int L = 3 * lane + k;
        const int P = L ^ ((L >> 3) & 7);
        wbuf[P] = (v4f){ p[4 * k + 0], p[4 * k + 1], p[4 * k + 2], p[4 * k + 3] };
    }
    __syncthreads();   // fence LDS writes -> reads

    float* ray_pts = out_pts + (size_t)ray * (NSTEPS * 3) + 768 * wv;  // wave's 768-float chunk
#pragma unroll
    for (int k = 0; k < 3; ++k) {
        const int L = 64 * k + lane;
        const int P = L ^ ((L >> 3) & 7);
        const v4f v = wbuf[P];
        *(v4f*)(ray_pts + 256 * k + 4 * lane) = v;   // fully coalesced: 16 lines/instr
    }
}

extern "C" void kernel_launch(void* const* d_in, const int* in_sizes, int n_in,
                              void* d_out, int out_size, void* d_ws, size_t ws_size,
                              hipStream_t stream) {
    const int*   occ    = (const int*)  d_in[0];  // bool -> int32
    const float* rays_o = (const float*)d_in[1];
    const float* rays_d = (const float*)d_in[2];
    const int*   bidx   = (const int*)  d_in[3];

    const int n_rays = in_sizes[3];
    const int n_vox  = in_sizes[0];               // 4*128^3 = 8388608
    const int n_words = n_vox / 32;               // 262144

    float* out      = (float*)d_out;
    float* out_pts  = out;                                    // [N,512,3]
    float* out_t    = out + (size_t)n_rays * NSTEPS * 3;      // [N,512]
    float* out_mask = out_t + (size_t)n_rays * NSTEPS;        // [N,512]

    unsigned int* bits = (unsigned int*)d_ws;                 // 1 MB tiled grid

    occ_pack_tiled_kernel<<<n_words / 256, 256, 0, stream>>>(occ, bits);
    occ_march_kernel<<<n_rays, 128, 0, stream>>>(bits, rays_o, rays_d, bidx,
                                                 out_pts, out_t, out_mask, n_rays);
}

// Round 8
// 365.512 us; speedup vs baseline: 1.2217x; 1.0038x over previous
//
#include <hip/hip_runtime.h>

constexpr int RESI   = 128;
constexpr int NSTEPS = 512;
// Tiled bitfield: 8x8x8 voxel block = 512 bits = 64 B = one cache line.
constexpr int GRID_WORDS_PER_BATCH = 65536;

typedef float v4f __attribute__((ext_vector_type(4)));
typedef int   v4i __attribute__((ext_vector_type(4)));

// Pack int32 0/1 occupancy -> tiled bitfield. One thread per output u32 word.
// Each z-row of 8 ints = 32B contiguous & 32B-aligned -> 2 x dwordx4 nt loads.
__global__ __launch_bounds__(256) void occ_pack_tiled_kernel(
    const int* __restrict__ occ, unsigned int* __restrict__ bits)
{
    const int w = blockIdx.x * blockDim.x + threadIdx.x;   // global word id
    const int b   = w >> 16;
    const int rem = w & 65535;
    const int blockid = rem >> 4;
    const int wib     = rem & 15;
    const int bx = blockid >> 8;
    const int by = (blockid >> 4) & 15;
    const int bz = blockid & 15;
    const int gx  = bx * 8 + (wib >> 1);
    const int gy0 = by * 8 + (wib & 1) * 4;
    const int gz0 = bz * 8;

    const int* __restrict__ src = occ + (((size_t)b * RESI + gx) * RESI + gy0) * RESI + gz0;

    unsigned int word = 0;
#pragma unroll
    for (int a = 0; a < 4; ++a) {
        const v4i lo = __builtin_nontemporal_load((const v4i*)(src + a * RESI));
        const v4i hi = __builtin_nontemporal_load((const v4i*)(src + a * RESI + 4));
        word |= (lo.x != 0 ? 1u : 0u) << (a * 8 + 0);
        word |= (lo.y != 0 ? 1u : 0u) << (a * 8 + 1);
        word |= (lo.z != 0 ? 1u : 0u) << (a * 8 + 2);
        word |= (lo.w != 0 ? 1u : 0u) << (a * 8 + 3);
        word |= (hi.x != 0 ? 1u : 0u) << (a * 8 + 4);
        word |= (hi.y != 0 ? 1u : 0u) << (a * 8 + 5);
        word |= (hi.z != 0 ? 1u : 0u) << (a * 8 + 6);
        word |= (hi.w != 0 ? 1u : 0u) << (a * 8 + 7);
    }
    bits[w] = word;
}

__global__ __launch_bounds__(128) void occ_march_kernel(
    const unsigned int* __restrict__ gridbits,  // tiled, [4, 65536]
    const float* __restrict__ rays_o,           // [N,3]
    const float* __restrict__ rays_d,           // [N,3]
    const int*   __restrict__ rays_bidx,        // [N]
    float*       __restrict__ out_pts,          // [N,512,3]
    float*       __restrict__ out_t,            // [N,512]
    float*       __restrict__ out_mask,         // [N,512] as 0.0/1.0
    int n_rays)
{
#pragma clang fp contract(off)
    // Per-wave pts staging: 192 slots x 16B = 3KB/wave, 2 waves = 6KB/block.
    __shared__ v4f sp[192 * 2];

    const int ray = blockIdx.x;
    if (ray >= n_rays) return;

    const int tid  = threadIdx.x;
    const int lane = tid & 63;
    const int wv   = tid >> 6;
    const int s0   = tid * 4;

    const float ox = rays_o[3 * ray + 0];
    const float oy = rays_o[3 * ray + 1];
    const float oz = rays_o[3 * ray + 2];
    const float dx = rays_d[3 * ray + 0];
    const float dy = rays_d[3 * ray + 1];
    const float dz = rays_d[3 * ray + 2];
    const int   b  = rays_bidx[ray];

    // safe_d / inv_d exactly as the reference (fp32 IEEE div, no fast-math)
    const float eps = 1e-10f;
    const float sdx = (fabsf(dx) < eps) ? ((dx >= 0.0f) ? eps : -eps) : dx;
    const float sdy = (fabsf(dy) < eps) ? ((dy >= 0.0f) ? eps : -eps) : dy;
    const float sdz = (fabsf(dz) < eps) ? ((dz >= 0.0f) ? eps : -eps) : dz;
    const float invx = 1.0f / sdx;
    const float invy = 1.0f / sdy;
    const float invz = 1.0f / sdz;

    const float t0x = (-1.0f - ox) * invx;
    const float t1x = ( 1.0f - ox) * invx;
    const float t0y = (-1.0f - oy) * invy;
    const float t1y = ( 1.0f - oy) * invy;
    const float t0z = (-1.0f - oz) * invz;
    const float t1z = ( 1.0f - oz) * invz;

    const float tmin = fmaxf(fmaxf(fminf(t0x, t1x), fminf(t0y, t1y)), fminf(t0z, t1z));
    const float tmax = fminf(fminf(fmaxf(t0x, t1x), fmaxf(t0y, t1y)), fmaxf(t0z, t1z));
    const float nearv  = fmaxf(tmin, 0.0f);
    const bool  ray_ok = (tmax > nearv);

    const unsigned int* __restrict__ gb = gridbits + (size_t)b * GRID_WORDS_PER_BATCH;

    float tv[4], px[4], py[4], pz[4];
    unsigned int widx[4], bitpos[4];
    bool in_box[4];

    // Phase 1: addresses + positions (no loads yet)
#pragma unroll
    for (int i = 0; i < 4; ++i) {
        const int s = s0 + i;
        const float ts = nearv + ((float)s + 0.5f) * 0.005f;   // mul+add, not fused
        const float x = ox + ts * dx;                           // mul+add, not fused
        const float y = oy + ts * dy;
        const float z = oz + ts * dz;
        tv[i] = ts; px[i] = x; py[i] = y; pz[i] = z;
        in_box[i] = ray_ok && (ts < tmax);

        int gx = (int)((x * 0.5f + 0.5f) * 128.0f);
        int gy = (int)((y * 0.5f + 0.5f) * 128.0f);
        int gz = (int)((z * 0.5f + 0.5f) * 128.0f);
        gx = min(max(gx, 0), RESI - 1);
        gy = min(max(gy, 0), RESI - 1);
        gz = min(max(gz, 0), RESI - 1);

        const unsigned int blockid = ((unsigned)(gx >> 3) << 8) |
                                     ((unsigned)(gy >> 3) << 4) |
                                      (unsigned)(gz >> 3);
        const unsigned int wib = (((unsigned)gx & 7u) << 1) | (((unsigned)gy >> 2) & 1u);
        widx[i]   = (blockid << 4) | wib;
        bitpos[i] = (((unsigned)gy & 3u) << 3) | ((unsigned)gz & 7u);
    }

    // Phase 2: 4 independent gathers in flight
    unsigned int wrd[4];
#pragma unroll
    for (int i = 0; i < 4; ++i) wrd[i] = gb[widx[i]];

    // Phase 3: masks
    float mv[4], p[12];
#pragma unroll
    for (int i = 0; i < 4; ++i) {
        const bool m = in_box[i] && ((wrd[i] >> bitpos[i]) & 1u);
        mv[i] = m ? 1.0f : 0.0f;
        p[3 * i + 0] = m ? px[i] : 0.0f;
        p[3 * i + 1] = m ? py[i] : 0.0f;
        p[3 * i + 2] = m ? pz[i] : 0.0f;
    }

    const size_t base = (size_t)ray * NSTEPS + (size_t)s0;

    // t / mask: lane-contiguous float4 streams (1 req/line).
    const v4f vt = { tv[0], tv[1], tv[2], tv[3] };
    const v4f vm = { mv[0], mv[1], mv[2], mv[3] };
    *(v4f*)(out_t    + base) = vt;
    *(v4f*)(out_mask + base) = vm;

    // pts: transpose through LDS so global stores are lane-contiguous float4.
    // Wave region = 192 16B slots (3KB). Logical slot L; phys P = L ^ ((L>>3)&7)
    // keeps 16B alignment; write phase conflict-free, read phase 2-way (free).
    v4f* wbuf = sp + 192 * wv;
#pragma unroll
    for (int k = 0; k < 3; ++k) {
        const int L = 3 * lane + k;
        const int P = L ^ ((L >> 3) & 7);
        wbuf[P] = (v4f){ p[4 * k + 0], p[4 * k + 1], p[4 * k + 2], p[4 * k + 3] };
    }
    __syncthreads();   // fence LDS writes -> reads

    float* ray_pts = out_pts + (size_t)ray * (NSTEPS * 3) + 768 * wv;  // wave's 768-float chunk
#pragma unroll
    for (int k = 0; k < 3; ++k) {
        const int L = 64 * k + lane;
        const int P = L ^ ((L >> 3) & 7);
        const v4f v = wbuf[P];
        *(v4f*)(ray_pts + 256 * k + 4 * lane) = v;   // fully coalesced: 16 lines/instr
    }
}

extern "C" void kernel_launch(void* const* d_in, const int* in_sizes, int n_in,
                              void* d_out, int out_size, void* d_ws, size_t ws_size,
                              hipStream_t stream) {
    const int*   occ    = (const int*)  d_in[0];  // bool -> int32
    const float* rays_o = (const float*)d_in[1];
    const float* rays_d = (const float*)d_in[2];
    const int*   bidx   = (const int*)  d_in[3];

    const int n_rays = in_sizes[3];
    const int n_vox  = in_sizes[0];               // 4*128^3 = 8388608
    const int n_words = n_vox / 32;               // 262144

    float* out      = (float*)d_out;
    float* out_pts  = out;                                    // [N,512,3]
    float* out_t    = out + (size_t)n_rays * NSTEPS * 3;      // [N,512]
    float* out_mask = out_t + (size_t)n_rays * NSTEPS;        // [N,512]

    unsigned int* bits = (unsigned int*)d_ws;                 // 1 MB tiled grid

    occ_pack_tiled_kernel<<<n_words / 256, 256, 0, stream>>>(occ, bits);
    occ_march_kernel<<<n_rays, 128, 0, stream>>>(bits, rays_o, rays_d, bidx,
                                                 out_pts, out_t, out_mask, n_rays);
}